// Round 1
// baseline (815.999 us; speedup 1.0000x reference)
//
#include <hip/hip_runtime.h>
#include <hip/hip_bf16.h>

#define M_ROWS 12288
#define N_COLS 12288
#define DDIM   128
#define MAXN   768          // max supported degree; binomial(12288,0.002) max ~46, huge margin
#define INV_T  (1.0f / 0.07f)

// One block per anchor row m. 256 threads = 4 waves.
// Phase 1: scan adj[m,:] (604 MB total across grid -> the HBM roofline term)
// Phase 2: y_m = xa[m] @ W  (in-block, W is L2-resident)
// Phase 3: scores s_j = y_m . input[n_j] / T   (one wave per neighbor)
// Phase 4: softmax over ~25 scores (serial, negligible)
// Phase 5: out[m] = sum_j w_j * input[n_j]
__global__ __launch_bounds__(256)
void layerconv_main(const float* __restrict__ xa,
                    const float* __restrict__ inp,
                    const int*   __restrict__ adj,
                    const float* __restrict__ wgt,
                    float*       __restrict__ out)
{
    const int m    = blockIdx.x;
    const int tid  = threadIdx.x;
    const int lane = tid & 63;
    const int wid  = tid >> 6;

    __shared__ float xarow[DDIM];
    __shared__ float ypart[2][DDIM];
    __shared__ float yrow[DDIM];
    __shared__ int   idx[MAXN];
    __shared__ float sc[MAXN];
    __shared__ int   cnt;
    __shared__ float inv_sum_s;

    if (tid == 0) cnt = 0;
    if (tid < DDIM) xarow[tid] = xa[(size_t)m * DDIM + tid];
    __syncthreads();

    // ---- Phase 1: adjacency row scan, int4-vectorized (12 iters/thread) ----
    {
        const int4* arow = (const int4*)(adj + (size_t)m * N_COLS);
        #pragma unroll
        for (int i = tid; i < N_COLS / 4; i += 256) {
            const int4 a = arow[i];
            if (a.x > 0) { int p = atomicAdd(&cnt, 1); if (p < MAXN) idx[p] = 4*i+0; }
            if (a.y > 0) { int p = atomicAdd(&cnt, 1); if (p < MAXN) idx[p] = 4*i+1; }
            if (a.z > 0) { int p = atomicAdd(&cnt, 1); if (p < MAXN) idx[p] = 4*i+2; }
            if (a.w > 0) { int p = atomicAdd(&cnt, 1); if (p < MAXN) idx[p] = 4*i+3; }
        }
    }

    // ---- Phase 2: y_m = xa_row @ W, split-K across the two thread-halves ----
    {
        const int c  = tid & 127;            // output column
        const int kh = tid >> 7;             // K half: 0 -> k in [0,64), 1 -> [64,128)
        float acc = 0.f;
        const float* wp = wgt + (size_t)(kh * 64) * DDIM + c;
        #pragma unroll 8
        for (int k = 0; k < 64; ++k)
            acc = fmaf(xarow[kh * 64 + k], wp[(size_t)k * DDIM], acc);
        ypart[kh][c] = acc;
    }
    __syncthreads();

    if (tid < DDIM) yrow[tid] = ypart[0][tid] + ypart[1][tid];
    const int cn = min(cnt, MAXN);           // cnt is stable since last barrier
    __syncthreads();

    // ---- Phase 3: neighbor dot products, one wave per neighbor ----
    {
        const float y0 = yrow[2 * lane];
        const float y1 = yrow[2 * lane + 1];
        for (int j = wid; j < cn; j += 4) {
            const float2 v = ((const float2*)(inp + (size_t)idx[j] * DDIM))[lane];
            float s = fmaf(y0, v.x, y1 * v.y);
            #pragma unroll
            for (int off = 32; off > 0; off >>= 1) s += __shfl_down(s, off);
            if (lane == 0) sc[j] = s * INV_T;
        }
    }
    __syncthreads();

    // ---- Phase 4: softmax over cn scores (cn ~ 25; serial is fine) ----
    if (tid == 0) {
        float mx = -INFINITY;
        for (int j = 0; j < cn; ++j) mx = fmaxf(mx, sc[j]);
        float sum = 0.f;
        for (int j = 0; j < cn; ++j) { float e = __expf(sc[j] - mx); sc[j] = e; sum += e; }
        inv_sum_s = 1.f / sum;
    }
    __syncthreads();

    // ---- Phase 5: out[m] = sum_j w_j * input[n_j]  (wave 0, float2 per lane) ----
    if (tid < 64) {
        float a0 = 0.f, a1 = 0.f;
        if (cn > 0) {
            for (int j = 0; j < cn; ++j) {
                const float  w = sc[j];
                const float2 v = ((const float2*)(inp + (size_t)idx[j] * DDIM))[tid];
                a0 = fmaf(w, v.x, a0);
                a1 = fmaf(w, v.y, a1);
            }
            const float is = inv_sum_s;
            a0 *= is; a1 *= is;
        } else {
            // All-masked row: softmax over identical NEG_PAD values is uniform
            // -> output is the column mean of input.
            for (int n = 0; n < N_COLS; ++n) {
                const float2 v = ((const float2*)(inp + (size_t)n * DDIM))[tid];
                a0 += v.x; a1 += v.y;
            }
            a0 /= (float)N_COLS; a1 /= (float)N_COLS;
        }
        ((float2*)(out + (size_t)m * DDIM))[tid] = make_float2(a0, a1);
    }
}

extern "C" void kernel_launch(void* const* d_in, const int* in_sizes, int n_in,
                              void* d_out, int out_size, void* d_ws, size_t ws_size,
                              hipStream_t stream) {
    const float* xa  = (const float*)d_in[0];   // xx_anchor [M, D] fp32
    const float* inp = (const float*)d_in[1];   // input     [N, D] fp32
    const int*   adj = (const int*)d_in[2];     // adj       [M, N] int32
    const float* wgt = (const float*)d_in[3];   // weight    [D, D] fp32
    float* out = (float*)d_out;                 // out       [M, D] fp32

    layerconv_main<<<M_ROWS, 256, 0, stream>>>(xa, inp, adj, wgt, out);
}